// Round 3
// baseline (1036.529 us; speedup 1.0000x reference)
//
#include <hip/hip_runtime.h>
#include <cstdint>
#include <cstddef>

#define TPB 256

// fc: feat0[n][b][c] = latents[b] . fc_W[:, n*64+c] + fc_b
__global__ __launch_bounds__(TPB) void k_fc(
    const float* __restrict__ lat, const float* __restrict__ W,
    const float* __restrict__ bias, float* __restrict__ out)
{
    int tid = blockIdx.x * TPB + threadIdx.x;   // 131072
    int c = tid & 63;
    int b = (tid >> 6) & 7;
    int n = tid >> 9;
    int j = n * 64 + c;
    float acc = bias[j];
    const float* lb = lat + b * 64;
#pragma unroll 16
    for (int l = 0; l < 64; ++l)
        acc = fmaf(lb[l], W[l * 16384 + j], acc);
    out[tid] = acc;
}

// Y[nb][co] = X[nb][:] . W[:][co]
template<int CI, int CO>
__global__ __launch_bounds__(TPB) void k_matw(
    const float* __restrict__ X, const float* __restrict__ W,
    float* __restrict__ Y, int NB)
{
    int tid = blockIdx.x * TPB + threadIdx.x;
    if (tid >= NB * CO) return;
    int co = tid % CO;
    int nb = tid / CO;
    const float* x = X + (size_t)nb * CI;
    float acc = 0.f;
#pragma unroll
    for (int ci = 0; ci < CI; ++ci)
        acc = fmaf(x[ci], W[ci * CO + co], acc);
    Y[tid] = acc;
}

__global__ __launch_bounds__(TPB) void k_zero2(float* a, int na, float* b, int nb)
{
    int tid = blockIdx.x * TPB + threadIdx.x;
    if (tid < na) a[tid] = 0.f;
    if (tid < nb) b[tid] = 0.f;
}

// Register-blocked tiled GEMM:
//   up[M][NTOT] += U[M][K] @ F[K][NTOT]  (+ UbW[row][col%CO] from kz==0 blocks)
// Block tile RT x NT, K-chunk KC=64 in LDS, thread tile R x C.
// Ratio = 4*R*C FMA per (R+C) ds_read_b128  (>=9.6 -> VALU-bound).
template<int K, int NTOT, int CO, int RT, int NT, int R, int C, int KSPLIT>
__global__ __launch_bounds__(TPB) void k_gemm2(
    const float* __restrict__ U, const float* __restrict__ F,
    const float* __restrict__ UbW, float* __restrict__ up)
{
    constexpr int KC = 64;
    constexpr int QC = KC / 4;              // 16 quads
    constexpr int RG = RT / R;              // threads in row dim
    constexpr int CG = NT / C;              // threads in col dim
    static_assert(RG * CG == TPB, "thread coverage");
    constexpr int KCHUNK = K / KSPLIT;
    static_assert(KCHUNK % KC == 0, "K chunking");

    __shared__ float u_lds[RT * KC];
    __shared__ float f_lds[QC * NT * 4];

    const int tid = threadIdx.x;
    const int tr = tid % RG;
    const int cg = tid / RG;
    const int row0 = blockIdx.x * RT;
    const int jc = blockIdx.y * NT;
    const int kz = blockIdx.z;
    const int kbase = kz * KCHUNK;

    float acc[R][C];
#pragma unroll
    for (int i = 0; i < R; ++i)
#pragma unroll
        for (int c = 0; c < C; ++c) acc[i][c] = 0.f;

    for (int kc = 0; kc < KCHUNK; kc += KC) {
        __syncthreads();
        // stage U tile (coalesced float4, XOR quad-swizzle into LDS)
#pragma unroll
        for (int l = tid; l < RT * QC; l += TPB) {
            int rr = l / QC, q = l % QC;
            float4 v = *reinterpret_cast<const float4*>(
                U + (size_t)(row0 + rr) * K + kbase + kc + 4 * q);
            int slot = q ^ (rr & 15);
            *reinterpret_cast<float4*>(u_lds + rr * KC + 4 * slot) = v;
        }
        // stage F chunk in k-quad layout [q][j][k&3]
#pragma unroll
        for (int l = tid; l < KC * NT; l += TPB) {
            int kk = l / NT, j = l % NT;
            f_lds[(kk >> 2) * (NT * 4) + j * 4 + (kk & 3)] =
                F[(size_t)(kbase + kc + kk) * NTOT + jc + j];
        }
        __syncthreads();
#pragma unroll
        for (int q = 0; q < QC; ++q) {
            float4 u[R];
#pragma unroll
            for (int i = 0; i < R; ++i) {
                int rr = tr + RG * i;
                u[i] = *reinterpret_cast<const float4*>(
                    u_lds + rr * KC + 4 * (q ^ (rr & 15)));
            }
            const float* fb = f_lds + q * (NT * 4) + (cg * C) * 4;
#pragma unroll
            for (int c = 0; c < C; ++c) {
                float4 f = *reinterpret_cast<const float4*>(fb + 4 * c);
#pragma unroll
                for (int i = 0; i < R; ++i) {
                    acc[i][c] = fmaf(u[i].x, f.x, acc[i][c]);
                    acc[i][c] = fmaf(u[i].y, f.y, acc[i][c]);
                    acc[i][c] = fmaf(u[i].z, f.z, acc[i][c]);
                    acc[i][c] = fmaf(u[i].w, f.w, acc[i][c]);
                }
            }
        }
    }
#pragma unroll
    for (int i = 0; i < R; ++i) {
        int row = row0 + tr + RG * i;
#pragma unroll
        for (int c = 0; c < C; ++c) {
            int col = jc + cg * C + c;
            float v = acc[i][c];
            if (kz == 0) v += UbW[(size_t)row * CO + (col % CO)];
            atomicAdd(&up[(size_t)row * NTOT + col], v);
        }
    }
}

// agg[rows[e]][j0..j0+3] += vals[e] * up[cols[e]][j0..j0+3]
template<int BC>
__global__ __launch_bounds__(TPB) void k_scatter4(
    const float* __restrict__ up, const int* __restrict__ rows,
    const int* __restrict__ cols, const float* __restrict__ vals,
    float* __restrict__ agg, int E)
{
    constexpr int JQ = BC / 4;
    int tid = blockIdx.x * TPB + threadIdx.x;
    if (tid >= E * JQ) return;
    int e = tid / JQ;
    int j0 = (tid % JQ) * 4;
    float v = vals[e];
    int c = cols[e], rr = rows[e];
    float4 u = *reinterpret_cast<const float4*>(&up[(size_t)c * BC + j0]);
    float* a = &agg[(size_t)rr * BC + j0];
    atomicAdd(a + 0, v * u.x);
    atomicAdd(a + 1, v * u.y);
    atomicAdd(a + 2, v * u.z);
    atomicAdd(a + 3, v * u.w);
}

template<int CO>
__global__ __launch_bounds__(TPB) void k_relu_bias(
    const float* __restrict__ agg, const float* __restrict__ bias,
    float* __restrict__ out, int n)
{
    int tid = blockIdx.x * TPB + threadIdx.x;
    if (tid >= n) return;
    float x = agg[tid] + bias[tid % CO];
    out[tid] = fmaxf(x, 0.f);
}

// out[b][n][j] = relu(agg[n][b*3+j] + bias[j]),  agg: [16384][24]
__global__ __launch_bounds__(TPB) void k_out(
    const float* __restrict__ agg, const float* __restrict__ bias,
    float* __restrict__ out)
{
    int tid = blockIdx.x * TPB + threadIdx.x;   // 393216
    int j = tid % 3;
    int n = (tid / 3) & 16383;
    int b = tid / 49152;
    float x = agg[(size_t)n * 24 + b * 3 + j] + bias[j];
    out[tid] = fmaxf(x, 0.f);
}

extern "C" void kernel_launch(void* const* d_in, const int* in_sizes, int n_in,
                              void* d_out, int out_size, void* d_ws, size_t ws_size,
                              hipStream_t stream)
{
    const float* lat   = (const float*)d_in[0];
    const float* fcW   = (const float*)d_in[1];
    const float* fcb   = (const float*)d_in[2];
    const float* U0    = (const float*)d_in[3];
    const float* Ub0   = (const float*)d_in[4];
    const float* W0    = (const float*)d_in[5];
    const float* b0    = (const float*)d_in[6];
    const float* vals0 = (const float*)d_in[7];
    const int*   rows0 = (const int*)d_in[8];
    const int*   cols0 = (const int*)d_in[9];
    const float* U1    = (const float*)d_in[10];
    const float* Ub1   = (const float*)d_in[11];
    const float* W1    = (const float*)d_in[12];
    const float* b1    = (const float*)d_in[13];
    const float* vals1 = (const float*)d_in[14];
    const int*   rows1 = (const int*)d_in[15];
    const int*   cols1 = (const int*)d_in[16];
    const float* U2    = (const float*)d_in[17];
    const float* Ub2   = (const float*)d_in[18];
    const float* W2    = (const float*)d_in[19];
    const float* b2    = (const float*)d_in[20];
    const float* vals2 = (const float*)d_in[21];
    const int*   rows2 = (const int*)d_in[22];
    const int*   cols2 = (const int*)d_in[23];

    float* ws    = (float*)d_ws;
    float* featA = ws;                  // 1048576 floats
    float* featB = featA + 1048576;     // 1048576
    float* fWb   = featB + 1048576;     // 262144
    float* UbWb  = fWb   + 262144;      // 131072
    float* up    = UbWb  + 131072;      // 1048576
    float* agg   = up    + 1048576;     // 1048576

    float* out = (float*)d_out;

    // fc -> featA = feat0 [256][8][64]
    hipLaunchKernelGGL(k_fc, dim3(131072 / TPB), dim3(TPB), 0, stream, lat, fcW, fcb, featA);

    // ---- layer 0: M=1024 K=256 NTOT=512 CO=64 ----
    hipLaunchKernelGGL((k_matw<64, 64>), dim3(131072 / TPB), dim3(TPB), 0, stream, featA, W0, fWb, 2048);
    hipLaunchKernelGGL((k_matw<64, 64>), dim3(65536 / TPB), dim3(TPB), 0, stream, Ub0, W0, UbWb, 1024);
    hipLaunchKernelGGL(k_zero2, dim3(524288 / TPB), dim3(TPB), 0, stream, up, 524288, agg, 524288);
    hipLaunchKernelGGL((k_gemm2<256, 512, 64, 128, 64, 4, 8, 4>), dim3(8, 8, 4), dim3(TPB), 0, stream, U0, fWb, UbWb, up);
    hipLaunchKernelGGL((k_scatter4<512>), dim3(2097152 / TPB), dim3(TPB), 0, stream, up, rows0, cols0, vals0, agg, 16384);
    hipLaunchKernelGGL((k_relu_bias<64>), dim3(524288 / TPB), dim3(TPB), 0, stream, agg, b0, featB, 524288);

    // ---- layer 1: M=4096 K=1024 NTOT=256 CO=32 ----
    hipLaunchKernelGGL((k_matw<64, 32>), dim3(262144 / TPB), dim3(TPB), 0, stream, featB, W1, fWb, 8192);
    hipLaunchKernelGGL((k_matw<64, 32>), dim3(131072 / TPB), dim3(TPB), 0, stream, Ub1, W1, UbWb, 4096);
    hipLaunchKernelGGL(k_zero2, dim3(1048576 / TPB), dim3(TPB), 0, stream, up, 1048576, agg, 1048576);
    hipLaunchKernelGGL((k_gemm2<1024, 256, 32, 128, 64, 4, 8, 4>), dim3(32, 4, 4), dim3(TPB), 0, stream, U1, fWb, UbWb, up);
    hipLaunchKernelGGL((k_scatter4<256>), dim3(4194304 / TPB), dim3(TPB), 0, stream, up, rows1, cols1, vals1, agg, 65536);
    hipLaunchKernelGGL((k_relu_bias<32>), dim3(1048576 / TPB), dim3(TPB), 0, stream, agg, b1, featA, 1048576);

    // ---- layer 2: M=16384 K=4096 NTOT=24 CO=3 ----
    hipLaunchKernelGGL((k_matw<32, 3>), dim3((98304 + TPB - 1) / TPB), dim3(TPB), 0, stream, featA, W2, fWb, 32768);
    hipLaunchKernelGGL((k_matw<32, 3>), dim3((49152 + TPB - 1) / TPB), dim3(TPB), 0, stream, Ub2, W2, UbWb, 16384);
    hipLaunchKernelGGL(k_zero2, dim3(393216 / TPB), dim3(TPB), 0, stream, up, 393216, agg, 393216);
    hipLaunchKernelGGL((k_gemm2<4096, 24, 3, 256, 24, 4, 6, 8>), dim3(64, 1, 8), dim3(TPB), 0, stream, U2, fWb, UbWb, up);
    hipLaunchKernelGGL((k_scatter4<24>), dim3((1572864 + TPB - 1) / TPB), dim3(TPB), 0, stream, up, rows2, cols2, vals2, agg, 262144);
    hipLaunchKernelGGL(k_out, dim3(393216 / TPB), dim3(TPB), 0, stream, agg, b2, out);
}

// Round 4
// 316.763 us; speedup vs baseline: 3.2723x; 3.2723x over previous
//
#include <hip/hip_runtime.h>
#include <cstdint>
#include <cstddef>

#define TPB 256

__device__ __forceinline__ void async_copy16(float* lds, const float* g)
{
    __builtin_amdgcn_global_load_lds(
        (const __attribute__((address_space(1))) void*)g,
        (__attribute__((address_space(3))) void*)lds,
        16, 0, 0);
}

// fc: feat0[n][b][c] = latents[b] . fc_W[:, n*64+c] + fc_b
__global__ __launch_bounds__(TPB) void k_fc(
    const float* __restrict__ lat, const float* __restrict__ W,
    const float* __restrict__ bias, float* __restrict__ out)
{
    int tid = blockIdx.x * TPB + threadIdx.x;   // 131072
    int c = tid & 63;
    int b = (tid >> 6) & 7;
    int n = tid >> 9;
    int j = n * 64 + c;
    float acc = bias[j];
    const float* lb = lat + b * 64;
#pragma unroll 16
    for (int l = 0; l < 64; ++l)
        acc = fmaf(lb[l], W[l * 16384 + j], acc);
    out[tid] = acc;
}

// F = feat@W written in quad-major layout: [jt][chunk][q][jj][e]
// (k = node index n; col = b*CO+co; jt=col/NT, jj=col%NT; chunk=k/64, q=(k/4)%16, e=k%4)
template<int CI, int CO, int NT>
__global__ __launch_bounds__(TPB) void k_matwq(
    const float* __restrict__ X, const float* __restrict__ W,
    float* __restrict__ Fq, int NB, int Kf)
{
    int tid = blockIdx.x * TPB + threadIdx.x;
    if (tid >= NB * CO) return;
    int co = tid % CO;
    int nb = tid / CO;
    const float* x = X + (size_t)nb * CI;
    float acc = 0.f;
#pragma unroll
    for (int ci = 0; ci < CI; ++ci)
        acc = fmaf(x[ci], W[ci * CO + co], acc);
    int n = nb >> 3, b = nb & 7;
    int col = b * CO + co;
    int jt = col / NT, jj = col % NT;
    int chunk = n >> 6, q = (n >> 2) & 15, e = n & 3;
    size_t idx = ((size_t)(jt * (Kf >> 6) + chunk) * 16 + q) * (NT * 4) + jj * 4 + e;
    Fq[idx] = acc;
}

// UbW[row][co] = Ub[row][:] . W[:][co]  (plain row-major)
template<int CI, int CO>
__global__ __launch_bounds__(TPB) void k_matw(
    const float* __restrict__ X, const float* __restrict__ W,
    float* __restrict__ Y, int NB)
{
    int tid = blockIdx.x * TPB + threadIdx.x;
    if (tid >= NB * CO) return;
    int co = tid % CO;
    int nb = tid / CO;
    const float* x = X + (size_t)nb * CI;
    float acc = 0.f;
#pragma unroll
    for (int ci = 0; ci < CI; ++ci)
        acc = fmaf(x[ci], W[ci * CO + co], acc);
    Y[tid] = acc;
}

__global__ __launch_bounds__(TPB) void k_zero_f(float* a, int n)
{
    int tid = blockIdx.x * TPB + threadIdx.x;
    if (tid < n) a[tid] = 0.f;
}
__global__ __launch_bounds__(TPB) void k_zero_i(int* a, int n)
{
    int tid = blockIdx.x * TPB + threadIdx.x;
    if (tid < n) a[tid] = 0;
}

// ---------------- async double-buffered GEMM ----------------
// up[M][NTOT] (+)= U[M][K] @ Fq + UbW fold.  KC=64 chunks, global_load_lds
// staging with source-side XOR quad-swizzle, 2-phase prefetch.
template<int K, int NTOT, int CO, int RT, int NT, int R, int C, int KSPLIT>
__global__ __launch_bounds__(TPB, 2) void k_gemm3(
    const float* __restrict__ U, const float* __restrict__ Fq,
    const float* __restrict__ UbW, float* __restrict__ up)
{
    constexpr int KC = 64;
    constexpr int RG = RT / R;
    constexpr int CG = NT / C;
    static_assert(RG * CG == TPB, "thread coverage");
    static_assert(RG % 16 == 0 || RG == 16, "swizzle hoist");
    constexpr int KCHUNK = K / KSPLIT;
    constexpr int NCH = KCHUNK / KC;
    constexpr int UFL = RT * KC;          // floats per U buffer
    constexpr int FFL = KC * NT;          // floats per F buffer
    constexpr int UCALLS = UFL / 256;     // 1 KB per wave-call
    constexpr int FCALLS = FFL / 256;
    constexpr int UCPW = UCALLS / 4;
    static_assert(UCALLS % 4 == 0, "u calls per wave");

    __shared__ float ub[2][UFL];
    __shared__ float fb[2][FFL];

    const int tid = threadIdx.x;
    const int w = tid >> 6, lane = tid & 63;
    const int tr = tid % RG;
    const int cg = tid / RG;
    const int row0 = blockIdx.x * RT;
    const int jt = blockIdx.y;
    const int kz = blockIdx.z;

    const float* Ublk = U + (size_t)row0 * K + (size_t)kz * KCHUNK;
    const float* Fblk = Fq + ((size_t)jt * (K / KC) + (size_t)kz * NCH) * FFL;

    auto stage = [&](int t, int bsel) {
#pragma unroll
        for (int i = 0; i < UCPW; ++i) {
            int call = w * UCPW + i;
            int fo = call * 256 + lane * 4;      // linear LDS float offset
            int rr = fo / KC;
            int qp = (fo & (KC - 1)) >> 2;
            int q = qp ^ (rr & 15);              // pre-swizzled global source
            async_copy16(&ub[bsel][call * 256],
                         Ublk + (size_t)rr * K + t * KC + 4 * q);
        }
        const float* fsrc = Fblk + (size_t)t * FFL;
#pragma unroll
        for (int call = w; call < FCALLS; call += 4) {
            async_copy16(&fb[bsel][call * 256], fsrc + call * 256 + lane * 4);
        }
    };

    float acc[R][C];
#pragma unroll
    for (int i = 0; i < R; ++i)
#pragma unroll
        for (int c = 0; c < C; ++c) acc[i][c] = 0.f;

    stage(0, 0);
    __syncthreads();                              // drains vmcnt(0)

    const int sw = tr & 15;
    for (int t = 0; t < NCH; ++t) {
        int cur = t & 1;
        if (t + 1 < NCH) stage(t + 1, cur ^ 1);   // async prefetch next chunk
        const float* ubp = ub[cur];
        const float* fbp = fb[cur];
#pragma unroll
        for (int q = 0; q < KC / 4; ++q) {
            float4 u[R];
#pragma unroll
            for (int i = 0; i < R; ++i)
                u[i] = *reinterpret_cast<const float4*>(
                    ubp + (tr + RG * i) * KC + 4 * (q ^ sw));
            const float* fp = fbp + q * (NT * 4) + cg * C * 4;
#pragma unroll
            for (int c = 0; c < C; ++c) {
                float4 f = *reinterpret_cast<const float4*>(fp + 4 * c);
#pragma unroll
                for (int i = 0; i < R; ++i) {
                    acc[i][c] = fmaf(u[i].x, f.x, acc[i][c]);
                    acc[i][c] = fmaf(u[i].y, f.y, acc[i][c]);
                    acc[i][c] = fmaf(u[i].z, f.z, acc[i][c]);
                    acc[i][c] = fmaf(u[i].w, f.w, acc[i][c]);
                }
            }
        }
        __syncthreads();   // stage(t+1) landed; everyone done reading buf cur
    }

#pragma unroll
    for (int i = 0; i < R; ++i) {
        int row = row0 + tr + RG * i;
#pragma unroll
        for (int c = 0; c < C; ++c) {
            int col = jt * NT + cg * C + c;
            float v = acc[i][c];
            if (KSPLIT == 1) {
                up[(size_t)row * NTOT + col] = v + UbW[(size_t)row * CO + col % CO];
            } else {
                if (kz == 0) v += UbW[(size_t)row * CO + col % CO];
                atomicAdd(&up[(size_t)row * NTOT + col], v);
            }
        }
    }
}

// ---------------- CSR build (per call) ----------------
__global__ __launch_bounds__(TPB) void k_hist(
    const int* __restrict__ r0, const int* __restrict__ r1,
    const int* __restrict__ r2, int* __restrict__ cnt)
{
    int e = blockIdx.x * TPB + threadIdx.x;      // 344064
    if (e < 16384)        atomicAdd(&cnt[r0[e]], 1);
    else if (e < 81920)   atomicAdd(&cnt[1024 + r1[e - 16384]], 1);
    else if (e < 344064)  atomicAdd(&cnt[5120 + r2[e - 81920]], 1);
}

// single-block exclusive scan over 21504 counts -> offs (and cursor copy)
__global__ __launch_bounds__(1024) void k_scan(
    const int* __restrict__ cnt, int* __restrict__ offs, int* __restrict__ cur)
{
    constexpr int N = 21504, PER = 21;
    __shared__ int wsum[16];
    int tid = threadIdx.x;
    int base = tid * PER;
    int c[PER];
    int s = 0;
#pragma unroll
    for (int i = 0; i < PER; ++i) { c[i] = s; s += cnt[base + i]; }
    int lane = tid & 63, w = tid >> 6;
    int v = s;
#pragma unroll
    for (int d = 1; d < 64; d <<= 1) {
        int t = __shfl_up(v, d);
        if (lane >= d) v += t;
    }
    if (lane == 63) wsum[w] = v;
    __syncthreads();
    int woff = 0;
    for (int i = 0; i < w; ++i) woff += wsum[i];
    int excl = woff + v - s;
#pragma unroll
    for (int i = 0; i < PER; ++i) {
        int o = excl + c[i];
        offs[base + i] = o;
        cur[base + i] = o;
    }
    if (tid == 1023) offs[N] = excl + s;
}

__global__ __launch_bounds__(TPB) void k_fill(
    const int* __restrict__ r0, const int* __restrict__ c0, const float* __restrict__ v0,
    const int* __restrict__ r1, const int* __restrict__ c1, const float* __restrict__ v1,
    const int* __restrict__ r2, const int* __restrict__ c2, const float* __restrict__ v2,
    int* __restrict__ cur, int* __restrict__ ccol, float* __restrict__ cval)
{
    int e = blockIdx.x * TPB + threadIdx.x;
    int rbase, col; float val;
    if (e < 16384)       { rbase = 0;    col = c0[e];         val = v0[e];         rbase += r0[e]; }
    else if (e < 81920)  { int l = e - 16384; rbase = 1024;  col = c1[l]; val = v1[l]; rbase += r1[l]; }
    else if (e < 344064) { int l = e - 81920; rbase = 5120;  col = c2[l]; val = v2[l]; rbase += r2[l]; }
    else return;
    int pos = atomicAdd(&cur[rbase], 1);
    ccol[pos] = col;
    cval[pos] = val;
}

// ---------------- CSR gather (= A @ up), relu+bias folded ----------------
template<int BC, int CO, int NR, int RBASE, bool FINAL>
__global__ __launch_bounds__(TPB) void k_gather(
    const float* __restrict__ up, const int* __restrict__ offs,
    const int* __restrict__ ccol, const float* __restrict__ cval,
    const float* __restrict__ bias, float* __restrict__ out)
{
    constexpr int JQ = BC / 4;
    int tid = blockIdx.x * TPB + threadIdx.x;
    if (tid >= NR * JQ) return;
    int jq = tid % JQ;
    int r = tid / JQ;
    int p0 = offs[RBASE + r], p1 = offs[RBASE + r + 1];
    float4 acc = make_float4(0.f, 0.f, 0.f, 0.f);
    for (int p = p0; p < p1; ++p) {
        float v = cval[p];
        int c = ccol[p];
        float4 u = *reinterpret_cast<const float4*>(&up[(size_t)c * BC + jq * 4]);
        acc.x = fmaf(v, u.x, acc.x);
        acc.y = fmaf(v, u.y, acc.y);
        acc.z = fmaf(v, u.z, acc.z);
        acc.w = fmaf(v, u.w, acc.w);
    }
    int col0 = jq * 4;
    if (!FINAL) {
        float4 o;
        o.x = fmaxf(acc.x + bias[(col0 + 0) % CO], 0.f);
        o.y = fmaxf(acc.y + bias[(col0 + 1) % CO], 0.f);
        o.z = fmaxf(acc.z + bias[(col0 + 2) % CO], 0.f);
        o.w = fmaxf(acc.w + bias[(col0 + 3) % CO], 0.f);
        *reinterpret_cast<float4*>(&out[(size_t)r * BC + col0]) = o;
    } else {
        // out[b][n][j] = relu(acc[e] + bias[j]), col = b*3 + j
        float a[4] = {acc.x, acc.y, acc.z, acc.w};
#pragma unroll
        for (int e = 0; e < 4; ++e) {
            int col = col0 + e;
            int b = col / 3, j = col - b * 3;
            out[(size_t)b * 49152 + (size_t)r * 3 + j] = fmaxf(a[e] + bias[j], 0.f);
        }
    }
}

extern "C" void kernel_launch(void* const* d_in, const int* in_sizes, int n_in,
                              void* d_out, int out_size, void* d_ws, size_t ws_size,
                              hipStream_t stream)
{
    const float* lat   = (const float*)d_in[0];
    const float* fcW   = (const float*)d_in[1];
    const float* fcb   = (const float*)d_in[2];
    const float* U0    = (const float*)d_in[3];
    const float* Ub0   = (const float*)d_in[4];
    const float* W0    = (const float*)d_in[5];
    const float* b0    = (const float*)d_in[6];
    const float* vals0 = (const float*)d_in[7];
    const int*   rows0 = (const int*)d_in[8];
    const int*   cols0 = (const int*)d_in[9];
    const float* U1    = (const float*)d_in[10];
    const float* Ub1   = (const float*)d_in[11];
    const float* W1    = (const float*)d_in[12];
    const float* b1    = (const float*)d_in[13];
    const float* vals1 = (const float*)d_in[14];
    const int*   rows1 = (const int*)d_in[15];
    const int*   cols1 = (const int*)d_in[16];
    const float* U2    = (const float*)d_in[17];
    const float* Ub2   = (const float*)d_in[18];
    const float* W2    = (const float*)d_in[19];
    const float* b2    = (const float*)d_in[20];
    const float* vals2 = (const float*)d_in[21];
    const int*   rows2 = (const int*)d_in[22];
    const int*   cols2 = (const int*)d_in[23];

    float* ws = (float*)d_ws;
    float* fbuf0 = ws;                    // 131072
    float* fbuf1 = fbuf0 + 131072;        // 524288
    float* fbuf2 = fbuf1 + 524288;        // 1048576
    float* fWq   = fbuf2 + 1048576;       // 262144
    float* UbW   = fWq   + 262144;        // 131072
    float* up    = UbW   + 131072;        // 1048576
    int*   offs  = (int*)(up + 1048576);  // 21760
    int*   cur   = offs + 21760;          // 21760
    int*   cnt   = cur + 21760;           // 21760
    int*   ccol  = cnt + 21760;           // 344064
    float* cval  = (float*)(ccol + 344064); // 344064

    float* out = (float*)d_out;

    // ---- CSR build (independent of features) ----
    hipLaunchKernelGGL(k_zero_i, dim3(84), dim3(TPB), 0, stream, cnt, 21504);
    hipLaunchKernelGGL(k_hist, dim3(1344), dim3(TPB), 0, stream, rows0, rows1, rows2, cnt);
    hipLaunchKernelGGL(k_scan, dim3(1), dim3(1024), 0, stream, cnt, offs, cur);
    hipLaunchKernelGGL(k_fill, dim3(1344), dim3(TPB), 0, stream,
                       rows0, cols0, vals0, rows1, cols1, vals1, rows2, cols2, vals2,
                       cur, ccol, cval);

    // ---- fc ----
    hipLaunchKernelGGL(k_fc, dim3(512), dim3(TPB), 0, stream, lat, fcW, fcb, fbuf0);

    // ---- layer 0: M=1024 K=256 NTOT=512 CO=64 ----
    hipLaunchKernelGGL((k_matwq<64, 64, 64>), dim3(512), dim3(TPB), 0, stream, fbuf0, W0, fWq, 2048, 256);
    hipLaunchKernelGGL((k_matw<64, 64>), dim3(256), dim3(TPB), 0, stream, Ub0, W0, UbW, 1024);
    hipLaunchKernelGGL((k_gemm3<256, 512, 64, 64, 64, 4, 4, 1>), dim3(16, 8, 1), dim3(TPB), 0, stream,
                       U0, fWq, UbW, up);
    hipLaunchKernelGGL((k_gather<512, 64, 1024, 0, false>), dim3(512), dim3(TPB), 0, stream,
                       up, offs, ccol, cval, b0, fbuf1);

    // ---- layer 1: M=4096 K=1024 NTOT=256 CO=32 ----
    hipLaunchKernelGGL((k_matwq<64, 32, 64>), dim3(1024), dim3(TPB), 0, stream, fbuf1, W1, fWq, 8192, 1024);
    hipLaunchKernelGGL((k_matw<64, 32>), dim3(512), dim3(TPB), 0, stream, Ub1, W1, UbW, 4096);
    hipLaunchKernelGGL(k_zero_f, dim3(4096), dim3(TPB), 0, stream, up, 1048576);
    hipLaunchKernelGGL((k_gemm3<1024, 256, 32, 64, 64, 4, 4, 2>), dim3(64, 4, 2), dim3(TPB), 0, stream,
                       U1, fWq, UbW, up);
    hipLaunchKernelGGL((k_gather<256, 32, 4096, 1024, false>), dim3(1024), dim3(TPB), 0, stream,
                       up, offs, ccol, cval, b1, fbuf2);

    // ---- layer 2: M=16384 K=4096 NTOT=24 CO=3 ----
    hipLaunchKernelGGL((k_matwq<32, 3, 24>), dim3(384), dim3(TPB), 0, stream, fbuf2, W2, fWq, 32768, 4096);
    hipLaunchKernelGGL((k_matw<32, 3>), dim3(192), dim3(TPB), 0, stream, Ub2, W2, UbW, 16384);
    hipLaunchKernelGGL(k_zero_f, dim3(1536), dim3(TPB), 0, stream, up, 393216);
    hipLaunchKernelGGL((k_gemm3<4096, 24, 3, 128, 24, 4, 3, 4>), dim3(128, 1, 4), dim3(TPB), 0, stream,
                       U2, fWq, UbW, up);
    hipLaunchKernelGGL((k_gather<24, 3, 16384, 5120, true>), dim3(384), dim3(TPB), 0, stream,
                       up, offs, ccol, cval, b2, out);
}

// Round 5
// 215.905 us; speedup vs baseline: 4.8009x; 1.4671x over previous
//
#include <hip/hip_runtime.h>
#include <cstdint>
#include <cstddef>

#define TPB 256

typedef __bf16 bf16x8 __attribute__((ext_vector_type(8)));
typedef float f32x4 __attribute__((ext_vector_type(4)));

union FragU { ushort u[8]; uint4 q; bf16x8 v; };

__device__ __forceinline__ ushort f2bf(float f)
{
    union { float f; uint32_t u; } v; v.f = f;
    uint32_t r = v.u + 0x7FFFu + ((v.u >> 16) & 1u);   // RNE
    return (ushort)(r >> 16);
}

// fc: feat0[n][b][c] = latents[b] . fc_W[:, n*64+c] + fc_b
__global__ __launch_bounds__(TPB) void k_fc(
    const float* __restrict__ lat, const float* __restrict__ W,
    const float* __restrict__ bias, float* __restrict__ out)
{
    int tid = blockIdx.x * TPB + threadIdx.x;   // 131072
    int c = tid & 63;
    int b = (tid >> 6) & 7;
    int n = tid >> 9;
    int j = n * 64 + c;
    float acc = bias[j];
    const float* lb = lat + b * 64;
#pragma unroll 16
    for (int l = 0; l < 64; ++l)
        acc = fmaf(lb[l], W[l * 16384 + j], acc);
    out[tid] = acc;
}

// F = feat@W, written directly in MFMA B-fragment order (bf16):
// elem (k=n, col=b*CO+co) -> Fq[(((ct*(KF/32)+ks)*4+kq)*16+cl)*8+j]
template<int CI, int CO, int KF>
__global__ __launch_bounds__(TPB) void k_matwfrag(
    const float* __restrict__ X, const float* __restrict__ W,
    ushort* __restrict__ Fq, int NBCO)
{
    int tid = blockIdx.x * TPB + threadIdx.x;
    if (tid >= NBCO) return;
    int co = tid % CO;
    int nb = tid / CO;
    const float* x = X + (size_t)nb * CI;
    float acc = 0.f;
#pragma unroll
    for (int ci = 0; ci < CI; ++ci)
        acc = fmaf(x[ci], W[ci * CO + co], acc);
    int n = nb >> 3, bb = nb & 7;
    int col = bb * CO + co;
    int ks = n >> 5, r = n & 31, kq = r >> 3, j = r & 7;
    int ct = col >> 4, cl = col & 15;
    size_t idx = ((((size_t)ct * (KF / 32) + ks) * 4 + kq) * 16 + cl) * 8 + j;
    Fq[idx] = f2bf(acc);
}

// UbW[row][co] = Ub[row][:] . W[:][co]
template<int CI, int CO>
__global__ __launch_bounds__(TPB) void k_matw(
    const float* __restrict__ X, const float* __restrict__ W,
    float* __restrict__ Y, int NB)
{
    int tid = blockIdx.x * TPB + threadIdx.x;
    if (tid >= NB * CO) return;
    int co = tid % CO;
    int nb = tid / CO;
    const float* x = X + (size_t)nb * CI;
    float acc = 0.f;
#pragma unroll
    for (int ci = 0; ci < CI; ++ci)
        acc = fmaf(x[ci], W[ci * CO + co], acc);
    Y[tid] = acc;
}

__global__ __launch_bounds__(TPB) void k_zero_f(float* a, int n)
{
    int tid = blockIdx.x * TPB + threadIdx.x;
    if (tid < n) a[tid] = 0.f;
}
__global__ __launch_bounds__(TPB) void k_zero_i(int* a, int n)
{
    int tid = blockIdx.x * TPB + threadIdx.x;
    if (tid < n) a[tid] = 0;
}

// ---------------- LDS-free MFMA GEMM ----------------
// up[M][NTOT] (+)= U[M][K](fp32->bf16) @ Fq(bf16 frags) + UbW fold.
// Wave computes RF*16 rows x 32 cols; A frags loaded straight from global
// (one 128B line per row per k-step), B frags lane-linear coalesced.
#define LOAD_STEP(S, t)                                                     \
    if ((t) < KS) {                                                         \
        _Pragma("unroll")                                                   \
        for (int rf = 0; rf < RF; ++rf) {                                   \
            a[S][rf][0] = *reinterpret_cast<const float4*>(Ap[rf] + (t) * 32);     \
            a[S][rf][1] = *reinterpret_cast<const float4*>(Ap[rf] + (t) * 32 + 4); \
        }                                                                   \
        _Pragma("unroll")                                                   \
        for (int cf = 0; cf < 2; ++cf)                                      \
            b[S][cf] = *reinterpret_cast<const uint4*>(Bp[cf] + (t) * 512); \
    }

#define COMP_STEP(S)                                                        \
    {                                                                       \
        _Pragma("unroll")                                                   \
        for (int rf = 0; rf < RF; ++rf) {                                   \
            FragU af;                                                       \
            const float* fa = reinterpret_cast<const float*>(&a[S][rf][0]); \
            _Pragma("unroll")                                               \
            for (int j = 0; j < 8; ++j) af.u[j] = f2bf(fa[j]);              \
            _Pragma("unroll")                                               \
            for (int cf = 0; cf < 2; ++cf) {                                \
                FragU bfr; bfr.q = b[S][cf];                                \
                acc[rf][cf] = __builtin_amdgcn_mfma_f32_16x16x32_bf16(      \
                    af.v, bfr.v, acc[rf][cf], 0, 0, 0);                     \
            }                                                               \
        }                                                                   \
    }

template<int K, int NTOT, int CO, int RF, int KSPLIT, bool ATOMIC>
__global__ __launch_bounds__(TPB) void k_gemm_mfma(
    const float* __restrict__ U, const ushort* __restrict__ Fq,
    const float* __restrict__ UbW, float* __restrict__ up)
{
    constexpr int KCH = K / KSPLIT;
    constexpr int KS = KCH / 32;
    static_assert(KS % 2 == 0, "even k-steps");

    const int lane = threadIdx.x & 63;
    const int w = threadIdx.x >> 6;
    const int rowbase = (blockIdx.x * 4 + w) * (RF * 16);
    const int jt = blockIdx.y;
    const int kz = blockIdx.z;
    const int kq = lane >> 4;
    const int m = lane & 15;

    const float* Ap[RF];
#pragma unroll
    for (int rf = 0; rf < RF; ++rf)
        Ap[rf] = U + (size_t)(rowbase + rf * 16 + m) * K + kz * KCH + kq * 8;

    const ushort* Bp[2];
#pragma unroll
    for (int cf = 0; cf < 2; ++cf)
        Bp[cf] = Fq + ((size_t)((jt * 2 + cf) * (K / 32) + (kz * KCH) / 32) * 64 + lane) * 8;

    f32x4 acc[RF][2];
#pragma unroll
    for (int rf = 0; rf < RF; ++rf)
#pragma unroll
        for (int cf = 0; cf < 2; ++cf)
            acc[rf][cf] = (f32x4){0.f, 0.f, 0.f, 0.f};

    float4 a[2][RF][2];
    uint4  b[2][2];

    LOAD_STEP(0, 0)
    for (int t = 0; t < KS; t += 2) {
        LOAD_STEP(1, t + 1)
        COMP_STEP(0)
        LOAD_STEP(0, t + 2)
        COMP_STEP(1)
    }

#pragma unroll
    for (int rf = 0; rf < RF; ++rf)
#pragma unroll
        for (int cf = 0; cf < 2; ++cf)
#pragma unroll
            for (int r = 0; r < 4; ++r) {
                int row = rowbase + rf * 16 + kq * 4 + r;
                int col = jt * 32 + cf * 16 + m;
                if (col < NTOT) {
                    float v = acc[rf][cf][r];
                    if (!ATOMIC) {
                        up[(size_t)row * NTOT + col] =
                            v + UbW[(size_t)row * CO + col % CO];
                    } else {
                        if (kz == 0) v += UbW[(size_t)row * CO + col % CO];
                        atomicAdd(&up[(size_t)row * NTOT + col], v);
                    }
                }
            }
}

// ---------------- CSR build (per call) ----------------
__global__ __launch_bounds__(TPB) void k_hist(
    const int* __restrict__ r0, const int* __restrict__ r1,
    const int* __restrict__ r2, int* __restrict__ cnt)
{
    int e = blockIdx.x * TPB + threadIdx.x;      // 344064
    if (e < 16384)        atomicAdd(&cnt[r0[e]], 1);
    else if (e < 81920)   atomicAdd(&cnt[1024 + r1[e - 16384]], 1);
    else if (e < 344064)  atomicAdd(&cnt[5120 + r2[e - 81920]], 1);
}

__global__ __launch_bounds__(1024) void k_scan(
    const int* __restrict__ cnt, int* __restrict__ offs, int* __restrict__ cur)
{
    constexpr int N = 21504, PER = 21;
    __shared__ int wsum[16];
    int tid = threadIdx.x;
    int base = tid * PER;
    int c[PER];
    int s = 0;
#pragma unroll
    for (int i = 0; i < PER; ++i) { c[i] = s; s += cnt[base + i]; }
    int lane = tid & 63, w = tid >> 6;
    int v = s;
#pragma unroll
    for (int d = 1; d < 64; d <<= 1) {
        int t = __shfl_up(v, d);
        if (lane >= d) v += t;
    }
    if (lane == 63) wsum[w] = v;
    __syncthreads();
    int woff = 0;
    for (int i = 0; i < w; ++i) woff += wsum[i];
    int excl = woff + v - s;
#pragma unroll
    for (int i = 0; i < PER; ++i) {
        int o = excl + c[i];
        offs[base + i] = o;
        cur[base + i] = o;
    }
    if (tid == 1023) offs[N] = excl + s;
}

__global__ __launch_bounds__(TPB) void k_fill(
    const int* __restrict__ r0, const int* __restrict__ c0, const float* __restrict__ v0,
    const int* __restrict__ r1, const int* __restrict__ c1, const float* __restrict__ v1,
    const int* __restrict__ r2, const int* __restrict__ c2, const float* __restrict__ v2,
    int* __restrict__ cur, int* __restrict__ ccol, float* __restrict__ cval)
{
    int e = blockIdx.x * TPB + threadIdx.x;
    int rbase, col; float val;
    if (e < 16384)       { rbase = 0;    col = c0[e];         val = v0[e];         rbase += r0[e]; }
    else if (e < 81920)  { int l = e - 16384; rbase = 1024;  col = c1[l]; val = v1[l]; rbase += r1[l]; }
    else if (e < 344064) { int l = e - 81920; rbase = 5120;  col = c2[l]; val = v2[l]; rbase += r2[l]; }
    else return;
    int pos = atomicAdd(&cur[rbase], 1);
    ccol[pos] = col;
    cval[pos] = val;
}

// ---------------- CSR gather (= A @ up), relu+bias folded ----------------
template<int BC, int CO, int NR, int RBASE, bool FINAL>
__global__ __launch_bounds__(TPB) void k_gather(
    const float* __restrict__ up, const int* __restrict__ offs,
    const int* __restrict__ ccol, const float* __restrict__ cval,
    const float* __restrict__ bias, float* __restrict__ out)
{
    constexpr int JQ = BC / 4;
    int tid = blockIdx.x * TPB + threadIdx.x;
    if (tid >= NR * JQ) return;
    int jq = tid % JQ;
    int r = tid / JQ;
    int p0 = offs[RBASE + r], p1 = offs[RBASE + r + 1];
    float4 acc = make_float4(0.f, 0.f, 0.f, 0.f);
    for (int p = p0; p < p1; ++p) {
        float v = cval[p];
        int c = ccol[p];
        float4 u = *reinterpret_cast<const float4*>(&up[(size_t)c * BC + jq * 4]);
        acc.x = fmaf(v, u.x, acc.x);
        acc.y = fmaf(v, u.y, acc.y);
        acc.z = fmaf(v, u.z, acc.z);
        acc.w = fmaf(v, u.w, acc.w);
    }
    int col0 = jq * 4;
    if (!FINAL) {
        float4 o;
        o.x = fmaxf(acc.x + bias[(col0 + 0) % CO], 0.f);
        o.y = fmaxf(acc.y + bias[(col0 + 1) % CO], 0.f);
        o.z = fmaxf(acc.z + bias[(col0 + 2) % CO], 0.f);
        o.w = fmaxf(acc.w + bias[(col0 + 3) % CO], 0.f);
        *reinterpret_cast<float4*>(&out[(size_t)r * BC + col0]) = o;
    } else {
        float a[4] = {acc.x, acc.y, acc.z, acc.w};
#pragma unroll
        for (int e = 0; e < 4; ++e) {
            int col = col0 + e;
            int b = col / 3, j = col - b * 3;
            out[(size_t)b * 49152 + (size_t)r * 3 + j] = fmaxf(a[e] + bias[j], 0.f);
        }
    }
}

extern "C" void kernel_launch(void* const* d_in, const int* in_sizes, int n_in,
                              void* d_out, int out_size, void* d_ws, size_t ws_size,
                              hipStream_t stream)
{
    const float* lat   = (const float*)d_in[0];
    const float* fcW   = (const float*)d_in[1];
    const float* fcb   = (const float*)d_in[2];
    const float* U0    = (const float*)d_in[3];
    const float* Ub0   = (const float*)d_in[4];
    const float* W0    = (const float*)d_in[5];
    const float* b0    = (const float*)d_in[6];
    const float* vals0 = (const float*)d_in[7];
    const int*   rows0 = (const int*)d_in[8];
    const int*   cols0 = (const int*)d_in[9];
    const float* U1    = (const float*)d_in[10];
    const float* Ub1   = (const float*)d_in[11];
    const float* W1    = (const float*)d_in[12];
    const float* b1    = (const float*)d_in[13];
    const float* vals1 = (const float*)d_in[14];
    const int*   rows1 = (const int*)d_in[15];
    const int*   cols1 = (const int*)d_in[16];
    const float* U2    = (const float*)d_in[17];
    const float* Ub2   = (const float*)d_in[18];
    const float* W2    = (const float*)d_in[19];
    const float* b2    = (const float*)d_in[20];
    const float* vals2 = (const float*)d_in[21];
    const int*   rows2 = (const int*)d_in[22];
    const int*   cols2 = (const int*)d_in[23];

    float* ws = (float*)d_ws;
    float* fbuf0 = ws;                    // 131072
    float* fbuf1 = fbuf0 + 131072;        // 524288
    float* fbuf2 = fbuf1 + 524288;        // 1048576
    float* fWq   = fbuf2 + 1048576;       // 262144 (frag buffer, as ushort)
    float* UbW   = fWq   + 262144;        // 131072
    float* up    = UbW   + 131072;        // 1048576
    int*   offs  = (int*)(up + 1048576);  // 21760
    int*   cur   = offs + 21760;          // 21760
    int*   cnt   = cur + 21760;           // 21760
    int*   ccol  = cnt + 21760;           // 344064
    float* cval  = (float*)(ccol + 344064); // 344064

    ushort* Fq16 = (ushort*)fWq;
    float* out = (float*)d_out;

    // ---- CSR build ----
    hipLaunchKernelGGL(k_zero_i, dim3(84), dim3(TPB), 0, stream, cnt, 21504);
    hipLaunchKernelGGL(k_hist, dim3(1344), dim3(TPB), 0, stream, rows0, rows1, rows2, cnt);
    hipLaunchKernelGGL(k_scan, dim3(1), dim3(1024), 0, stream, cnt, offs, cur);
    hipLaunchKernelGGL(k_fill, dim3(1344), dim3(TPB), 0, stream,
                       rows0, cols0, vals0, rows1, cols1, vals1, rows2, cols2, vals2,
                       cur, ccol, cval);

    // ---- fc ----
    hipLaunchKernelGGL(k_fc, dim3(512), dim3(TPB), 0, stream, lat, fcW, fcb, fbuf0);

    // ---- layer 0: M=1024 K=256 NTOT=512 CO=64, RF=1, no split ----
    hipLaunchKernelGGL((k_matwfrag<64, 64, 256>), dim3(512), dim3(TPB), 0, stream, fbuf0, W0, Fq16, 131072);
    hipLaunchKernelGGL((k_matw<64, 64>), dim3(256), dim3(TPB), 0, stream, Ub0, W0, UbW, 1024);
    hipLaunchKernelGGL((k_gemm_mfma<256, 512, 64, 1, 1, false>), dim3(16, 16, 1), dim3(TPB), 0, stream,
                       U0, Fq16, UbW, up);
    hipLaunchKernelGGL((k_gather<512, 64, 1024, 0, false>), dim3(512), dim3(TPB), 0, stream,
                       up, offs, ccol, cval, b0, fbuf1);

    // ---- layer 1: M=4096 K=1024 NTOT=256 CO=32, RF=1, no split ----
    hipLaunchKernelGGL((k_matwfrag<64, 32, 1024>), dim3(1024), dim3(TPB), 0, stream, fbuf1, W1, Fq16, 262144);
    hipLaunchKernelGGL((k_matw<64, 32>), dim3(512), dim3(TPB), 0, stream, Ub1, W1, UbW, 4096);
    hipLaunchKernelGGL((k_gemm_mfma<1024, 256, 32, 1, 1, false>), dim3(64, 8, 1), dim3(TPB), 0, stream,
                       U1, Fq16, UbW, up);
    hipLaunchKernelGGL((k_gather<256, 32, 4096, 1024, false>), dim3(1024), dim3(TPB), 0, stream,
                       up, offs, ccol, cval, b1, fbuf2);

    // ---- layer 2: M=16384 K=4096 NTOT=24 (pad 32) CO=3, RF=2, KSPLIT=4 ----
    hipLaunchKernelGGL(k_zero_i, dim3(256), dim3(TPB), 0, stream, (int*)Fq16, 65536);
    hipLaunchKernelGGL((k_matwfrag<32, 3, 4096>), dim3(384), dim3(TPB), 0, stream, fbuf2, W2, Fq16, 98304);
    hipLaunchKernelGGL((k_matw<32, 3>), dim3(192), dim3(TPB), 0, stream, Ub2, W2, UbW, 16384);
    hipLaunchKernelGGL(k_zero_f, dim3(1536), dim3(TPB), 0, stream, up, 393216);
    hipLaunchKernelGGL((k_gemm_mfma<4096, 24, 3, 2, 4, true>), dim3(128, 1, 4), dim3(TPB), 0, stream,
                       U2, Fq16, UbW, up);
    hipLaunchKernelGGL((k_gather<24, 3, 16384, 5120, true>), dim3(384), dim3(TPB), 0, stream,
                       up, offs, ccol, cval, b2, out);
}